// Round 14
// baseline (2918.212 us; speedup 1.0000x reference)
//
#include <hip/hip_runtime.h>

#define BB 256
#define SEQ 512
#define IDIM 32
#define HDIM 128
#define ODIM 64
// dopri5, dt=1/2 (verified R9-R13: absmax 0.0156 vs threshold 0.0497).
#define NSUB_SIM 2

typedef float v2f __attribute__((ext_vector_type(2)));
typedef _Float16 hf;
typedef hf h2 __attribute__((ext_vector_type(2)));
typedef hf h8 __attribute__((ext_vector_type(8)));

__device__ __forceinline__ float fdot2(h2 a, h2 b, float c) {
#if __has_builtin(__builtin_amdgcn_fdot2)
    return __builtin_amdgcn_fdot2(a, b, c, false);
#else
    float r = c;
    asm volatile("v_dot2_f32_f16 %0, %1, %2, %0" : "+v"(r) : "v"(a), "v"(b));
    return r;
#endif
}

// ONE WAVE per chain (64 threads/block, 256 blocks = 1 chain/CU).
// Lane l owns full rows {2l, 2l+1}; W_h rows in VGPRs as f16 pairs, loaded
// VOLATILE so the compiler cannot rematerialize the loads inside the stage
// loop (the R6/R13 failure: VGPR=104/116 + FETCH doubled = per-stage L2
// weight reloads on the critical path).
// Per stage: pack a-pair -> 1 ds_write_b32 -> (same-wave in-order LDS, no
// barrier) -> 16 broadcast ds_read_b128 -> 128 v_dot2_f32_f16 (8 chains)
// -> local tail. Zero cross-lane ops, zero barriers.
__global__ __launch_bounds__(64, 1) void lnn_recur(
    const float* __restrict__ x,
    const float* __restrict__ Wx,
    const float* __restrict__ Wh,
    const float* __restrict__ bias,
    const float* __restrict__ tau,
    float* __restrict__ hs)
{
    __shared__ __align__(16) hf abh[2][HDIM];
    const int b  = blockIdx.x;
    const int l  = threadIdx.x;
    const int r0 = 2 * l;
    const int r1 = 2 * l + 1;

    const float K2E = 2.885390081777927f;  // 2*log2(e); tanh(z)=1-2/(1+exp2(K2E*z))

    // W_h rows r0, r1 as f16 pairs scaled by K2E — VOLATILE loads: must stay
    // in VGPRs (128 regs), cannot be re-loaded in the loop.
    h2 w0[64], w1[64];
    {
        const volatile float* p0 = Wh + r0 * HDIM;
        const volatile float* p1 = Wh + r1 * HDIM;
        #pragma unroll
        for (int m = 0; m < 64; ++m) {
            float a0 = p0[2*m], a1 = p0[2*m+1];
            float b0 = p1[2*m], b1 = p1[2*m+1];
            w0[m] = h2{(hf)(a0 * K2E), (hf)(a1 * K2E)};
            w1[m] = h2{(hf)(b0 * K2E), (hf)(b1 * K2E)};
        }
    }
    // W_x rows as f16 pairs scaled by K2E — volatile for the same reason.
    h2 wx0[16], wx1[16];
    {
        const volatile float* p0 = Wx + r0 * IDIM;
        const volatile float* p1 = Wx + r1 * IDIM;
        #pragma unroll
        for (int m = 0; m < 16; ++m) {
            float a0 = p0[2*m], a1 = p0[2*m+1];
            float b0 = p1[2*m], b1 = p1[2*m+1];
            wx0[m] = h2{(hf)(a0 * K2E), (hf)(a1 * K2E)};
            wx1[m] = h2{(hf)(b0 * K2E), (hf)(b1 * K2E)};
        }
    }

    const v2f bK  = v2f{K2E * bias[r0], K2E * bias[r1]};
    const float DT = 1.0f / (float)NSUB_SIM;
    const v2f dti = v2f{DT / (fabsf(tau[r0]) + 0.001f),
                        DT / (fabsf(tau[r1]) + 0.001f)};

    v2f hv = v2f{0.f, 0.f};
    int par = 0;

    // x_0 (all lanes same addresses -> L1 broadcast), converted per timestep
    float4 xf[8];
    #pragma unroll
    for (int m = 0; m < 8; ++m)
        xf[m] = *reinterpret_cast<const float4*>(x + (size_t)b * SEQ * IDIM + 4 * m);

    #pragma unroll 1
    for (int t = 0; t < SEQ; ++t) {
        // convert x_t to f16 pairs, then prefetch next x into xf
        h2 xq[16];
        #pragma unroll
        for (int m = 0; m < 8; ++m) {
            xq[2*m+0] = h2{(hf)xf[m].x, (hf)xf[m].y};
            xq[2*m+1] = h2{(hf)xf[m].z, (hf)xf[m].w};
        }
        const int tn = (t + 1 < SEQ) ? (t + 1) : t;
        #pragma unroll
        for (int m = 0; m < 8; ++m)
            xf[m] = *reinterpret_cast<const float4*>(x + ((size_t)b * SEQ + tn) * IDIM + 4 * m);

        // cbK = K2E*(x_t . Wx_row + bias), both rows, lane-local f16 dots
        v2f cb;
        {
            float c00 = 0.f, c01 = 0.f, c10 = 0.f, c11 = 0.f;
            #pragma unroll
            for (int m = 0; m < 8; ++m) {
                c00 = fdot2(wx0[2*m+0], xq[2*m+0], c00);
                c01 = fdot2(wx0[2*m+1], xq[2*m+1], c01);
                c10 = fdot2(wx1[2*m+0], xq[2*m+0], c10);
                c11 = fdot2(wx1[2*m+1], xq[2*m+1], c11);
            }
            cb = v2f{c00 + c01, c10 + c11} + bK;
        }

        #pragma unroll 1
        for (int s = 0; s < NSUB_SIM; ++s) {
            // m = dt*k = dti*(tanh(cbK + K2E*Wh.a) - a), fully lane-local
            auto stage = [&](v2f a) -> v2f {
                *reinterpret_cast<h2*>(&abh[par][r0]) = h2{(hf)a.x, (hf)a.y};
                asm volatile("" ::: "memory");   // compiler: keep write before reads
                const h8* ap = reinterpret_cast<const h8*>(&abh[par][0]);
                float p0a = 0.f, p0b = 0.f, p0c = 0.f, p0d = 0.f;
                float p1a = 0.f, p1b = 0.f, p1c = 0.f, p1d = 0.f;
                #pragma unroll
                for (int i = 0; i < 16; ++i) {
                    h8 va = ap[i];
                    h2 A0 = h2{va[0], va[1]};
                    h2 A1 = h2{va[2], va[3]};
                    h2 A2 = h2{va[4], va[5]};
                    h2 A3 = h2{va[6], va[7]};
                    p0a = fdot2(w0[4*i+0], A0, p0a);
                    p0b = fdot2(w0[4*i+1], A1, p0b);
                    p0c = fdot2(w0[4*i+2], A2, p0c);
                    p0d = fdot2(w0[4*i+3], A3, p0d);
                    p1a = fdot2(w1[4*i+0], A0, p1a);
                    p1b = fdot2(w1[4*i+1], A1, p1b);
                    p1c = fdot2(w1[4*i+2], A2, p1c);
                    p1d = fdot2(w1[4*i+3], A3, p1d);
                }
                par ^= 1;
                v2f z = cb + v2f{(p0a + p0b) + (p0c + p0d),
                                 (p1a + p1b) + (p1c + p1d)};
                float e0 = __builtin_amdgcn_exp2f(z.x);
                float e1 = __builtin_amdgcn_exp2f(z.y);
                v2f th = v2f{1.0f - 2.0f * __builtin_amdgcn_rcpf(1.0f + e0),
                             1.0f - 2.0f * __builtin_amdgcn_rcpf(1.0f + e1)};
                return dti * (th - a);
            };

            v2f m1 = stage(hv);
            v2f m2 = stage(hv + 0.2f * m1);
            v2f m3 = stage(hv + (0.075f * m1 + 0.225f * m2));
            v2f m4 = stage(hv + ((44.0f/45.0f) * m1 - (56.0f/15.0f) * m2) + (32.0f/9.0f) * m3);
            v2f m5 = stage(hv + ((19372.0f/6561.0f) * m1 - (25360.0f/2187.0f) * m2)
                              + ((64448.0f/6561.0f) * m3 - (212.0f/729.0f) * m4));
            v2f m6 = stage(hv + ((9017.0f/3168.0f) * m1 - (355.0f/33.0f) * m2)
                              + ((46732.0f/5247.0f) * m3 + (49.0f/176.0f) * m4)
                              - (5103.0f/18656.0f) * m5);
            hv = hv + (((35.0f/384.0f) * m1 + (500.0f/1113.0f) * m3)
                     + ((125.0f/192.0f) * m4 - (2187.0f/6784.0f) * m5))
                    + (11.0f/84.0f) * m6;
        }

        *reinterpret_cast<v2f*>(&hs[((size_t)b * SEQ + t) * HDIM + r0]) = hv;
    }
}

// outs[bt][o] = hs[bt] . Wout_row_o + bout[o]
__global__ __launch_bounds__(256) void lnn_out(
    const float* __restrict__ hs,
    const float* __restrict__ Wout,
    const float* __restrict__ bout,
    float* __restrict__ outs)
{
    __shared__ float wt[HDIM][ODIM + 1];
    const int tid = threadIdx.x;
    for (int i = tid; i < HDIM * ODIM; i += 256) {
        int o = i >> 7;
        int k = i & 127;
        wt[k][o] = Wout[i];
    }
    __syncthreads();

    const int o = tid & 63;
    const int r = tid >> 6;
    const float bo = bout[o];
    const int nbt = BB * SEQ;

    for (int bt = blockIdx.x * 4 + r; bt < nbt; bt += gridDim.x * 4) {
        const float4* hp = reinterpret_cast<const float4*>(hs + (size_t)bt * HDIM);
        float acc0 = bo, acc1 = 0.f, acc2 = 0.f, acc3 = 0.f;
        #pragma unroll
        for (int kk = 0; kk < 32; ++kk) {
            float4 v = hp[kk];
            acc0 += v.x * wt[4*kk+0][o];
            acc1 += v.y * wt[4*kk+1][o];
            acc2 += v.z * wt[4*kk+2][o];
            acc3 += v.w * wt[4*kk+3][o];
        }
        outs[(size_t)bt * ODIM + o] = (acc0 + acc1) + (acc2 + acc3);
    }
}

extern "C" void kernel_launch(void* const* d_in, const int* in_sizes, int n_in,
                              void* d_out, int out_size, void* d_ws, size_t ws_size,
                              hipStream_t stream) {
    const float* x    = (const float*)d_in[0];
    const float* Wx   = (const float*)d_in[1];
    const float* Wh   = (const float*)d_in[2];
    const float* bias = (const float*)d_in[3];
    const float* tau  = (const float*)d_in[4];
    const float* Wout = (const float*)d_in[5];
    const float* bout = (const float*)d_in[6];

    float* outs = (float*)d_out;
    float* hs   = outs + (size_t)BB * SEQ * ODIM;

    lnn_recur<<<BB, 64, 0, stream>>>(x, Wx, Wh, bias, tau, hs);
    lnn_out<<<2048, 256, 0, stream>>>(hs, Wout, bout, outs);
}

// Round 15
// 1377.931 us; speedup vs baseline: 2.1178x; 2.1178x over previous
//
#include <hip/hip_runtime.h>

#define BB 256
#define SEQ 512
#define IDIM 32
#define HDIM 128
#define ODIM 64
// Integrator: ETDRK4 (Cox-Matthews) with dt=1/2. The linear part -h/tau is
// DIAGONAL -> integrated exactly via elementwise exponentials; only the tanh
// nonlinearity goes through RK stages: 4 matvec-stages/substep vs dopri5's 6.
// 8 stages/timestep (vs R10's 12). Coefficients per-row, precomputed at init.
// Verified: exact for constant tanh-output (sum rule f1+2*f2p+f3 = 1-E).
#define NSUB_SIM 2

typedef float v2f __attribute__((ext_vector_type(2)));

template <int CTRL>
__device__ __forceinline__ float dpp_add(float x) {
    int yi = __builtin_amdgcn_mov_dpp(__float_as_int(x), CTRL, 0xF, 0xF, false);
    return x + __int_as_float(yi);
}

// One block (= one chain) per CU, 256 threads = 4 waves (R10 structure).
// Lane (g = tid>>3, c = tid&7): owns rows {4g..4g+3} x k-chunk [16c,16c+16).
// Per stage: 1 ds_write_b32 + lgkmcnt-only s_barrier + 4 ds_read_b128,
// 32 pk-FMA, DPP butterfly (0xB1, 0x4E, 0x141), 1-row tanh tail.
__global__ __launch_bounds__(256, 1) void lnn_recur(
    const float* __restrict__ x,
    const float* __restrict__ Wx,
    const float* __restrict__ Wh,
    const float* __restrict__ bias,
    const float* __restrict__ tau,
    float* __restrict__ hs)
{
    // a stored chunk-major: chunk c at [c][0..15], 4-float pad -> 80B stride
    __shared__ float abuf[2][8][20];
    const int b    = blockIdx.x;
    const int tid  = threadIdx.x;
    const int g    = tid >> 3;      // row group: rows 4g..4g+3
    const int c    = tid & 7;       // k-chunk
    const int rsel = c & 3;         // this lane's tail row: 4g+rsel
    const int row  = 4 * g + rsel;
    const bool pub = (c < 4);       // publisher lanes for the global h store

    const float K2E = 2.885390081777927f;  // 2*log2(e); tanh(z)=1-2/(1+exp2(K2E*z))

    // WhK: 4 rows x 16 k, scaled by K2E (64 VGPR)
    v2f wq[4][8];
    #pragma unroll
    for (int r = 0; r < 4; ++r) {
        const float* wrow = Wh + (4 * g + r) * HDIM + 16 * c;
        #pragma unroll
        for (int m = 0; m < 4; ++m) {
            float4 v = *reinterpret_cast<const float4*>(wrow + 4 * m);
            wq[r][2*m+0] = v2f{v.x * K2E, v.y * K2E};
            wq[r][2*m+1] = v2f{v.z * K2E, v.w * K2E};
        }
    }
    // WxK: 4 rows x 4 k (x-chunk [4c,4c+4)), scaled by K2E
    v2f wx[4][2];
    #pragma unroll
    for (int r = 0; r < 4; ++r) {
        float4 v = *reinterpret_cast<const float4*>(Wx + (4 * g + r) * IDIM + 4 * c);
        wx[r][0] = v2f{v.x * K2E, v.y * K2E};
        wx[r][1] = v2f{v.z * K2E, v.w * K2E};
    }
    const float biasK = K2E * bias[row];

    // --- ETDRK4 per-row coefficients (f32, init-time) ---
    // L = -1/tau', z = L*DT. Qa = (1-E2) [= L^{-1}(E2-1)*a], f-coeffs folded
    // with a = 1/tau' via a*DT = -z.
    const float DT  = 1.0f / (float)NSUB_SIM;
    const float tp  = fabsf(tau[row]) + 0.001f;
    const float av  = 1.0f / tp;
    const float zz  = -DT * av;
    const float Ee  = expf(zz);
    const float E2  = expf(0.5f * zz);
    const float Qa  = 1.0f - E2;
    const float iz2 = 1.0f / (zz * zz);
    const float f1a  = -(-4.0f - zz + Ee * (4.0f - 3.0f * zz + zz * zz)) * iz2;
    const float f2a2 = -2.0f * (2.0f + zz + Ee * (zz - 2.0f)) * iz2;
    const float f3a  = -(-4.0f - 3.0f * zz - zz * zz + Ee * (4.0f - zz)) * iz2;

    const bool selb0 = (c & 1) != 0;
    const bool selb1 = (c & 2) != 0;
    auto sel4 = [&](float d0, float d1, float d2, float d3) -> float {
        float lo = selb0 ? d1 : d0;
        float hi = selb0 ? d3 : d2;
        return selb1 ? hi : lo;
    };

    float h  = 0.0f;
    int  par = 0;
    float cb = 0.0f;

    float4 xv = *reinterpret_cast<const float4*>(x + ((size_t)b * SEQ) * IDIM + 4 * c);

    #pragma unroll 1
    for (int t = 0; t < SEQ; ++t) {
        const int tn = (t + 1 < SEQ) ? (t + 1) : t;
        float4 xn = *reinterpret_cast<const float4*>(x + ((size_t)b * SEQ + tn) * IDIM + 4 * c);

        // cbaseK = K2E*(x_t . Wx_row + bias) for this lane's row
        {
            v2f xa = v2f{xv.x, xv.y}, xb = v2f{xv.z, xv.w};
            float p[4];
            #pragma unroll
            for (int r = 0; r < 4; ++r) {
                v2f q = wx[r][0] * xa + wx[r][1] * xb;
                float d = q.x + q.y;
                d = dpp_add<0xB1>(d);
                d = dpp_add<0x4E>(d);
                d = dpp_add<0x141>(d);
                p[r] = d;
            }
            cb = sel4(p[0], p[1], p[2], p[3]) + biasK;
        }

        #pragma unroll 1
        for (int s = 0; s < NSUB_SIM; ++s) {
            // returns T = tanh(cb + Wh.a) for this lane's row; publishes a
            auto stage = [&](float a) -> float {
                abuf[par][g >> 2][4 * (g & 3) + rsel] = a;
                asm volatile("s_waitcnt lgkmcnt(0)" ::: "memory");
                __builtin_amdgcn_s_barrier();
                asm volatile("" ::: "memory");
                const float* ap = &abuf[par][c][0];
                float4 v0 = *reinterpret_cast<const float4*>(ap + 0);
                float4 v1 = *reinterpret_cast<const float4*>(ap + 4);
                float4 v2 = *reinterpret_cast<const float4*>(ap + 8);
                float4 v3 = *reinterpret_cast<const float4*>(ap + 12);
                v2f l0 = v2f{v0.x, v0.y}, h0 = v2f{v0.z, v0.w};
                v2f l1 = v2f{v1.x, v1.y}, h1 = v2f{v1.z, v1.w};
                v2f l2 = v2f{v2.x, v2.y}, h2 = v2f{v2.z, v2.w};
                v2f l3 = v2f{v3.x, v3.y}, h3 = v2f{v3.z, v3.w};
                float d[4];
                #pragma unroll
                for (int r = 0; r < 4; ++r) {
                    v2f acc0 = wq[r][0] * l0 + wq[r][1] * h0;
                    v2f acc1 = wq[r][2] * l1 + wq[r][3] * h1;
                    acc0 += wq[r][4] * l2; acc1 += wq[r][5] * h2;
                    acc0 += wq[r][6] * l3; acc1 += wq[r][7] * h3;
                    v2f accs = acc0 + acc1;
                    float dd = accs.x + accs.y;
                    dd = dpp_add<0xB1>(dd);    // + (c^1)
                    dd = dpp_add<0x4E>(dd);    // + (c^2): quad sum = k-half
                    dd = dpp_add<0x141>(dd);   // + other quad: full dot
                    d[r] = dd;
                }
                par ^= 1;
                float dd = sel4(d[0], d[1], d[2], d[3]);
                float e  = __builtin_amdgcn_exp2f(cb + dd);
                return 1.0f - 2.0f * __builtin_amdgcn_rcpf(1.0f + e);
            };

            // ETDRK4 (Cox-Matthews), L diagonal, N = a*tanh(.) folded into coeffs
            float T1 = stage(h);
            float u  = E2 * h + Qa * T1;
            float T2 = stage(u);
            float bb = E2 * h + Qa * T2;
            float T3 = stage(bb);
            float cc = E2 * u + Qa * (2.0f * T3 - T1);
            float T4 = stage(cc);
            h = Ee * h + f1a * T1 + f2a2 * (T2 + T3) + f3a * T4;
        }

        xv = xn;
        if (pub) hs[((size_t)b * SEQ + t) * HDIM + row] = h;
    }
}

// outs[bt][o] = hs[bt] . Wout_row_o + bout[o]
__global__ __launch_bounds__(256) void lnn_out(
    const float* __restrict__ hs,
    const float* __restrict__ Wout,
    const float* __restrict__ bout,
    float* __restrict__ outs)
{
    __shared__ float wt[HDIM][ODIM + 1];
    const int tid = threadIdx.x;
    for (int i = tid; i < HDIM * ODIM; i += 256) {
        int o = i >> 7;
        int k = i & 127;
        wt[k][o] = Wout[i];
    }
    __syncthreads();

    const int o = tid & 63;
    const int r = tid >> 6;
    const float bo = bout[o];
    const int nbt = BB * SEQ;

    for (int bt = blockIdx.x * 4 + r; bt < nbt; bt += gridDim.x * 4) {
        const float4* hp = reinterpret_cast<const float4*>(hs + (size_t)bt * HDIM);
        float acc0 = bo, acc1 = 0.f, acc2 = 0.f, acc3 = 0.f;
        #pragma unroll
        for (int kk = 0; kk < 32; ++kk) {
            float4 v = hp[kk];
            acc0 += v.x * wt[4*kk+0][o];
            acc1 += v.y * wt[4*kk+1][o];
            acc2 += v.z * wt[4*kk+2][o];
            acc3 += v.w * wt[4*kk+3][o];
        }
        outs[(size_t)bt * ODIM + o] = (acc0 + acc1) + (acc2 + acc3);
    }
}

extern "C" void kernel_launch(void* const* d_in, const int* in_sizes, int n_in,
                              void* d_out, int out_size, void* d_ws, size_t ws_size,
                              hipStream_t stream) {
    const float* x    = (const float*)d_in[0];
    const float* Wx   = (const float*)d_in[1];
    const float* Wh   = (const float*)d_in[2];
    const float* bias = (const float*)d_in[3];
    const float* tau  = (const float*)d_in[4];
    const float* Wout = (const float*)d_in[5];
    const float* bout = (const float*)d_in[6];

    float* outs = (float*)d_out;
    float* hs   = outs + (size_t)BB * SEQ * ODIM;

    lnn_recur<<<BB, 256, 0, stream>>>(x, Wx, Wh, bias, tau, hs);
    lnn_out<<<2048, 256, 0, stream>>>(hs, Wout, bout, outs);
}

// Round 16
// 1130.569 us; speedup vs baseline: 2.5812x; 1.2188x over previous
//
#include <hip/hip_runtime.h>

#define BB 256
#define SEQ 512
#define IDIM 32
#define HDIM 128
#define ODIM 64
// ETDRK4 (Cox-Matthews), dt=1/2: linear part exact, 8 stages/timestep.
// Verified R15: absmax 0.015625 vs threshold 0.0497. Error model (lambda_eff~3,
// calibrated on dopri5 dt-sweep) rules out dt=1 (est 0.27) and ETDRK3 (0.042).
#define NSUB_SIM 2

typedef float v2f __attribute__((ext_vector_type(2)));
typedef _Float16 hf;
typedef hf h2 __attribute__((ext_vector_type(2)));
typedef hf h8 __attribute__((ext_vector_type(8)));

template <int CTRL>
__device__ __forceinline__ float dpp_add(float x) {
    int yi = __builtin_amdgcn_mov_dpp(__float_as_int(x), CTRL, 0xF, 0xF, false);
    return x + __int_as_float(yi);
}

__device__ __forceinline__ float fdot2(h2 a, h2 b, float c) {
#if __has_builtin(__builtin_amdgcn_fdot2)
    return __builtin_amdgcn_fdot2(a, b, c, false);
#else
    float r = c;
    asm volatile("v_dot2_f32_f16 %0, %1, %2, %0" : "+v"(r) : "v"(a), "v"(b));
    return r;
#endif
}

// One block (= one chain) per CU, 256 threads = 4 waves.
// R16 tiling: lane (g = tid>>2, c = tid&3) owns rows {2g, 2g+1} x k-chunk
// [32c, 32c+32). f16 weights (32 VGPR). Per stage: 1 ds_write_b16 (2-dup per
// row) + lgkm-only s_barrier + 4 ds_read_b128 + 32 v_dot2_f32_f16 (4 chains,
// 8-deep) + 2-LEVEL DPP butterfly (xor1 0xB1, xor2 0x4E) + 1 cndmask + tail.
// vs R15: butterfly 3->2 levels, sel4->sel2, issue ~40% lower, same sync.
__global__ __launch_bounds__(256, 1) void lnn_recur(
    const float* __restrict__ x,
    const float* __restrict__ Wx,
    const float* __restrict__ Wh,
    const float* __restrict__ bias,
    const float* __restrict__ tau,
    float* __restrict__ hs)
{
    __shared__ __align__(16) hf abh[2][HDIM];
    const int b    = blockIdx.x;
    const int tid  = threadIdx.x;
    const int g    = tid >> 2;      // row pair: rows 2g, 2g+1  (g in [0,64))
    const int c    = tid & 3;       // k-chunk [32c, 32c+32)
    const int rsel = c & 1;         // this lane's tail row: 2g+rsel
    const int row  = 2 * g + rsel;
    const bool pub = (c < 2);       // publisher lanes for the global h store

    const float K2E = 2.885390081777927f;  // 2*log2(e); tanh(z)=1-2/(1+exp2(K2E*z))

    // Wh rows 2g,2g+1 x k-chunk as f16 pairs scaled by K2E (32 VGPR)
    h2 w0[16], w1[16];
    {
        const float* p0 = Wh + (2 * g + 0) * HDIM + 32 * c;
        const float* p1 = Wh + (2 * g + 1) * HDIM + 32 * c;
        #pragma unroll
        for (int m = 0; m < 16; ++m) {
            w0[m] = h2{(hf)(p0[2*m] * K2E), (hf)(p0[2*m+1] * K2E)};
            w1[m] = h2{(hf)(p1[2*m] * K2E), (hf)(p1[2*m+1] * K2E)};
        }
    }
    // Wx rows 2g,2g+1 x x-chunk [8c, 8c+8), scaled by K2E (f32 v2f, 16 VGPR)
    v2f wx[2][4];
    #pragma unroll
    for (int r = 0; r < 2; ++r) {
        const float* p = Wx + (2 * g + r) * IDIM + 8 * c;
        #pragma unroll
        for (int m = 0; m < 4; ++m)
            wx[r][m] = v2f{p[2*m] * K2E, p[2*m+1] * K2E};
    }
    const float biasK = K2E * bias[row];

    // ETDRK4 per-row coefficients (verified R15)
    const float DT  = 1.0f / (float)NSUB_SIM;
    const float tp  = fabsf(tau[row]) + 0.001f;
    const float zz  = -DT / tp;
    const float Ee  = expf(zz);
    const float E2  = expf(0.5f * zz);
    const float Qa  = 1.0f - E2;
    const float iz2 = 1.0f / (zz * zz);
    const float f1a  = -(-4.0f - zz + Ee * (4.0f - 3.0f * zz + zz * zz)) * iz2;
    const float f2a2 = -2.0f * (2.0f + zz + Ee * (zz - 2.0f)) * iz2;
    const float f3a  = -(-4.0f - 3.0f * zz - zz * zz + Ee * (4.0f - zz)) * iz2;

    float h  = 0.0f;
    int  par = 0;
    float cb = 0.0f;

    // x chunk [8c, 8c+8) = 2 float4, prefetched one timestep ahead
    float4 xv0 = *reinterpret_cast<const float4*>(x + ((size_t)b * SEQ) * IDIM + 8 * c);
    float4 xv1 = *reinterpret_cast<const float4*>(x + ((size_t)b * SEQ) * IDIM + 8 * c + 4);

    #pragma unroll 1
    for (int t = 0; t < SEQ; ++t) {
        const int tn = (t + 1 < SEQ) ? (t + 1) : t;
        float4 xn0 = *reinterpret_cast<const float4*>(x + ((size_t)b * SEQ + tn) * IDIM + 8 * c);
        float4 xn1 = *reinterpret_cast<const float4*>(x + ((size_t)b * SEQ + tn) * IDIM + 8 * c + 4);

        // cbK = K2E*(x_t . Wx_row + bias): 2-level butterfly over c, sel2
        {
            v2f xa0 = v2f{xv0.x, xv0.y}, xa1 = v2f{xv0.z, xv0.w};
            v2f xa2 = v2f{xv1.x, xv1.y}, xa3 = v2f{xv1.z, xv1.w};
            float p[2];
            #pragma unroll
            for (int r = 0; r < 2; ++r) {
                v2f q = (wx[r][0] * xa0 + wx[r][1] * xa1)
                      + (wx[r][2] * xa2 + wx[r][3] * xa3);
                float d = q.x + q.y;
                d = dpp_add<0xB1>(d);   // + (c^1)
                d = dpp_add<0x4E>(d);   // + (c^2): full 32-k sum
                p[r] = d;
            }
            cb = (rsel ? p[1] : p[0]) + biasK;
        }

        #pragma unroll 1
        for (int s = 0; s < NSUB_SIM; ++s) {
            // returns T = tanh(cb + Wh.a) for this lane's row; publishes a (f16)
            auto stage = [&](float a) -> float {
                abh[par][row] = (hf)a;   // 2-dup same-addr same-data write
                asm volatile("s_waitcnt lgkmcnt(0)" ::: "memory");
                __builtin_amdgcn_s_barrier();
                asm volatile("" ::: "memory");
                const h8* ap = reinterpret_cast<const h8*>(&abh[par][32 * c]);
                h8 q0 = ap[0], q1 = ap[1], q2 = ap[2], q3 = ap[3];
                float p0a = 0.f, p0b = 0.f, p1a = 0.f, p1b = 0.f;
                #pragma unroll
                for (int j = 0; j < 4; ++j) {
                    h2 A0 = h2{q0[2*j], q0[2*j+1]};
                    h2 A1 = h2{q1[2*j], q1[2*j+1]};
                    h2 A2 = h2{q2[2*j], q2[2*j+1]};
                    h2 A3 = h2{q3[2*j], q3[2*j+1]};
                    p0a = fdot2(w0[j],      A0, p0a);
                    p0b = fdot2(w0[4 + j],  A1, p0b);
                    p0a = fdot2(w0[8 + j],  A2, p0a);
                    p0b = fdot2(w0[12 + j], A3, p0b);
                    p1a = fdot2(w1[j],      A0, p1a);
                    p1b = fdot2(w1[4 + j],  A1, p1b);
                    p1a = fdot2(w1[8 + j],  A2, p1a);
                    p1b = fdot2(w1[12 + j], A3, p1b);
                }
                float d0 = p0a + p0b;
                float d1 = p1a + p1b;
                d0 = dpp_add<0xB1>(d0); d0 = dpp_add<0x4E>(d0);
                d1 = dpp_add<0xB1>(d1); d1 = dpp_add<0x4E>(d1);
                par ^= 1;
                float dd = rsel ? d1 : d0;
                float e  = __builtin_amdgcn_exp2f(cb + dd);
                return 1.0f - 2.0f * __builtin_amdgcn_rcpf(1.0f + e);
            };

            // ETDRK4 (Cox-Matthews), diagonal L, N folded into coefficients
            float T1 = stage(h);
            float u  = E2 * h + Qa * T1;
            float T2 = stage(u);
            float bb = E2 * h + Qa * T2;
            float T3 = stage(bb);
            float cc = E2 * u + Qa * (2.0f * T3 - T1);
            float T4 = stage(cc);
            h = Ee * h + f1a * T1 + f2a2 * (T2 + T3) + f3a * T4;
        }

        xv0 = xn0; xv1 = xn1;
        if (pub) hs[((size_t)b * SEQ + t) * HDIM + row] = h;
    }
}

// outs[bt][o] = hs[bt] . Wout_row_o + bout[o]
__global__ __launch_bounds__(256) void lnn_out(
    const float* __restrict__ hs,
    const float* __restrict__ Wout,
    const float* __restrict__ bout,
    float* __restrict__ outs)
{
    __shared__ float wt[HDIM][ODIM + 1];
    const int tid = threadIdx.x;
    for (int i = tid; i < HDIM * ODIM; i += 256) {
        int o = i >> 7;
        int k = i & 127;
        wt[k][o] = Wout[i];
    }
    __syncthreads();

    const int o = tid & 63;
    const int r = tid >> 6;
    const float bo = bout[o];
    const int nbt = BB * SEQ;

    for (int bt = blockIdx.x * 4 + r; bt < nbt; bt += gridDim.x * 4) {
        const float4* hp = reinterpret_cast<const float4*>(hs + (size_t)bt * HDIM);
        float acc0 = bo, acc1 = 0.f, acc2 = 0.f, acc3 = 0.f;
        #pragma unroll
        for (int kk = 0; kk < 32; ++kk) {
            float4 v = hp[kk];
            acc0 += v.x * wt[4*kk+0][o];
            acc1 += v.y * wt[4*kk+1][o];
            acc2 += v.z * wt[4*kk+2][o];
            acc3 += v.w * wt[4*kk+3][o];
        }
        outs[(size_t)bt * ODIM + o] = (acc0 + acc1) + (acc2 + acc3);
    }
}

extern "C" void kernel_launch(void* const* d_in, const int* in_sizes, int n_in,
                              void* d_out, int out_size, void* d_ws, size_t ws_size,
                              hipStream_t stream) {
    const float* x    = (const float*)d_in[0];
    const float* Wx   = (const float*)d_in[1];
    const float* Wh   = (const float*)d_in[2];
    const float* bias = (const float*)d_in[3];
    const float* tau  = (const float*)d_in[4];
    const float* Wout = (const float*)d_in[5];
    const float* bout = (const float*)d_in[6];

    float* outs = (float*)d_out;
    float* hs   = outs + (size_t)BB * SEQ * ODIM;

    lnn_recur<<<BB, 256, 0, stream>>>(x, Wx, Wh, bias, tau, hs);
    lnn_out<<<2048, 256, 0, stream>>>(hs, Wout, bout, outs);
}